// Round 1
// baseline (1424.256 us; speedup 1.0000x reference)
//
#include <hip/hip_runtime.h>
#include <hip/hip_bf16.h>
#include <math.h>

#define N 4096
#define D 128
#define NJ 4
#define KTOP 16
#define ROWS 4   // feature rows per block

__global__ __launch_bounds__(256) void
neguni_main(const float* __restrict__ feat, const int* __restrict__ target,
            const float* __restrict__ negs, const int* __restrict__ idxp,
            float* __restrict__ out)
{
    __shared__ __align__(16) float f_lds[ROWS][D];
    __shared__ float tops[ROWS][NJ][KTOP];
    __shared__ int tgt_s[ROWS];

    const int tid  = threadIdx.x;
    const int wave = tid >> 6;     // = j (0..3)
    const int lane = tid & 63;
    const int row0 = blockIdx.x * ROWS;
    const int idx  = idxp[0];

    // ---- load + L2-normalize the ROWS feature rows (wave w -> row row0+w) ----
    {
        const int r = row0 + wave;
        float a0 = feat[r * D + 2 * lane];
        float a1 = feat[r * D + 2 * lane + 1];
        float ss = a0 * a0 + a1 * a1;
        #pragma unroll
        for (int off = 32; off > 0; off >>= 1) ss += __shfl_xor(ss, off, 64);
        float inv = 1.0f / fmaxf(sqrtf(ss), 1e-12f);
        f_lds[wave][2 * lane]     = a0 * inv;
        f_lds[wave][2 * lane + 1] = a1 * inv;
        if (lane == 0) tgt_s[wave] = target[r];
    }
    __syncthreads();

    const int tr0 = tgt_s[0], tr1 = tgt_s[1], tr2 = tgt_s[2], tr3 = tgt_s[3];

    // per-lane descending top-16 list per row
    float lst[ROWS][KTOP];
    #pragma unroll
    for (int r = 0; r < ROWS; r++)
        #pragma unroll
        for (int k = 0; k < KTOP; k++) lst[r][k] = -3.0e38f;

    const float* nj = negs + (size_t)wave * N * D;
    const bool do_mask = (wave == idx);

    for (int c = 0; c < N; c += 256) {
        const int m0 = c + lane;
        const float4* bp0 = (const float4*)(nj + (size_t)(m0)       * D);
        const float4* bp1 = (const float4*)(nj + (size_t)(m0 + 64)  * D);
        const float4* bp2 = (const float4*)(nj + (size_t)(m0 + 128) * D);
        const float4* bp3 = (const float4*)(nj + (size_t)(m0 + 192) * D);

        float dot[4][ROWS];
        float ss4[4];
        #pragma unroll
        for (int q = 0; q < 4; q++) {
            ss4[q] = 0.f;
            #pragma unroll
            for (int r = 0; r < ROWS; r++) dot[q][r] = 0.f;
        }

        #pragma unroll 4
        for (int kk = 0; kk < D / 4; kk++) {
            float4 f0 = ((const float4*)f_lds[0])[kk];
            float4 f1 = ((const float4*)f_lds[1])[kk];
            float4 f2 = ((const float4*)f_lds[2])[kk];
            float4 f3 = ((const float4*)f_lds[3])[kk];

            float4 b0 = bp0[kk];
            float4 b1 = bp1[kk];
            float4 b2 = bp2[kk];
            float4 b3 = bp3[kk];

            ss4[0] += b0.x*b0.x + b0.y*b0.y + b0.z*b0.z + b0.w*b0.w;
            ss4[1] += b1.x*b1.x + b1.y*b1.y + b1.z*b1.z + b1.w*b1.w;
            ss4[2] += b2.x*b2.x + b2.y*b2.y + b2.z*b2.z + b2.w*b2.w;
            ss4[3] += b3.x*b3.x + b3.y*b3.y + b3.z*b3.z + b3.w*b3.w;

            dot[0][0] += b0.x*f0.x + b0.y*f0.y + b0.z*f0.z + b0.w*f0.w;
            dot[0][1] += b0.x*f1.x + b0.y*f1.y + b0.z*f1.z + b0.w*f1.w;
            dot[0][2] += b0.x*f2.x + b0.y*f2.y + b0.z*f2.z + b0.w*f2.w;
            dot[0][3] += b0.x*f3.x + b0.y*f3.y + b0.z*f3.z + b0.w*f3.w;

            dot[1][0] += b1.x*f0.x + b1.y*f0.y + b1.z*f0.z + b1.w*f0.w;
            dot[1][1] += b1.x*f1.x + b1.y*f1.y + b1.z*f1.z + b1.w*f1.w;
            dot[1][2] += b1.x*f2.x + b1.y*f2.y + b1.z*f2.z + b1.w*f2.w;
            dot[1][3] += b1.x*f3.x + b1.y*f3.y + b1.z*f3.z + b1.w*f3.w;

            dot[2][0] += b2.x*f0.x + b2.y*f0.y + b2.z*f0.z + b2.w*f0.w;
            dot[2][1] += b2.x*f1.x + b2.y*f1.y + b2.z*f1.z + b2.w*f1.w;
            dot[2][2] += b2.x*f2.x + b2.y*f2.y + b2.z*f2.z + b2.w*f2.w;
            dot[2][3] += b2.x*f3.x + b2.y*f3.y + b2.z*f3.z + b2.w*f3.w;

            dot[3][0] += b3.x*f0.x + b3.y*f0.y + b3.z*f0.z + b3.w*f0.w;
            dot[3][1] += b3.x*f1.x + b3.y*f1.y + b3.z*f1.z + b3.w*f1.w;
            dot[3][2] += b3.x*f2.x + b3.y*f2.y + b3.z*f2.z + b3.w*f2.w;
            dot[3][3] += b3.x*f3.x + b3.y*f3.y + b3.z*f3.z + b3.w*f3.w;
        }

        #pragma unroll
        for (int q = 0; q < 4; q++) {
            const int m = m0 + 64 * q;
            const float inv = 1.0f / fmaxf(sqrtf(ss4[q]), 1e-12f);
            int tm = 0;
            if (do_mask) tm = target[m];
            float s0 = dot[q][0] * inv;
            float s1 = dot[q][1] * inv;
            float s2 = dot[q][2] * inv;
            float s3 = dot[q][3] * inv;
            if (do_mask) {
                if (tm == tr0) s0 = -1e9f;
                if (tm == tr1) s1 = -1e9f;
                if (tm == tr2) s2 = -1e9f;
                if (tm == tr3) s3 = -1e9f;
            }
            // trickle-insert into each row's sorted (desc) list
            {
                float v = s0;
                if (v > lst[0][KTOP-1]) {
                    #pragma unroll
                    for (int i = 0; i < KTOP; i++) {
                        float cur = lst[0][i]; bool gt = v > cur;
                        lst[0][i] = gt ? v : cur; v = gt ? cur : v;
                    }
                }
            }
            {
                float v = s1;
                if (v > lst[1][KTOP-1]) {
                    #pragma unroll
                    for (int i = 0; i < KTOP; i++) {
                        float cur = lst[1][i]; bool gt = v > cur;
                        lst[1][i] = gt ? v : cur; v = gt ? cur : v;
                    }
                }
            }
            {
                float v = s2;
                if (v > lst[2][KTOP-1]) {
                    #pragma unroll
                    for (int i = 0; i < KTOP; i++) {
                        float cur = lst[2][i]; bool gt = v > cur;
                        lst[2][i] = gt ? v : cur; v = gt ? cur : v;
                    }
                }
            }
            {
                float v = s3;
                if (v > lst[3][KTOP-1]) {
                    #pragma unroll
                    for (int i = 0; i < KTOP; i++) {
                        float cur = lst[3][i]; bool gt = v > cur;
                        lst[3][i] = gt ? v : cur; v = gt ? cur : v;
                    }
                }
            }
        }
    }

    // ---- wave-level merge: 64 sorted lists -> exact top-16 per (row, j) ----
    #pragma unroll
    for (int r = 0; r < ROWS; r++) {
        #pragma unroll
        for (int it = 0; it < KTOP; it++) {
            float head = lst[r][0];
            float mx = head;
            #pragma unroll
            for (int off = 32; off > 0; off >>= 1) mx = fmaxf(mx, __shfl_xor(mx, off, 64));
            unsigned long long b = __ballot(head == mx);
            int winner = __ffsll((unsigned long long)b) - 1;
            if (lane == winner) {
                #pragma unroll
                for (int i = 0; i < KTOP - 1; i++) lst[r][i] = lst[r][i + 1];
                lst[r][KTOP - 1] = -3.0e38f;
            }
            if (lane == 0) tops[r][wave][it] = mx;
        }
    }
    __syncthreads();

    // ---- epilogue: wave w handles row w; lanes 0..15 = k positions ----
    {
        const int r = wave;
        const int k = lane & 15;
        float l0 = tops[r][0][k] * 100.0f;   // 1/TEMP
        float l1 = tops[r][1][k] * 100.0f;
        float l2 = tops[r][2][k] * 100.0f;
        float l3 = tops[r][3][k] * 100.0f;
        float m = fmaxf(fmaxf(l0, l1), fmaxf(l2, l3));
        float d0 = l0 - m, d1 = l1 - m, d2 = l2 - m, d3 = l3 - m;
        float e0 = expf(d0), e1 = expf(d1), e2 = expf(d2), e3 = expf(d3);
        float s = e0 + e1 + e2 + e3;
        float ent = (e0*d0 + e1*d1 + e2*d2 + e3*d3) / s - logf(s);

        float wk = powf(0.95f, (float)k);
        float Ssum = (1.0f - powf(0.95f, 16.0f)) / 0.05f;
        float val = ent * wk / Ssum;
        if (lane >= 16) val = 0.f;
        #pragma unroll
        for (int off = 32; off > 0; off >>= 1) val += __shfl_xor(val, off, 64);
        if (lane == 0) atomicAdd(out, val * (1.0f / (float)N));
    }

    if (blockIdx.x == 0 && tid == 0) atomicAdd(out, logf(4.0f));
}

extern "C" void kernel_launch(void* const* d_in, const int* in_sizes, int n_in,
                              void* d_out, int out_size, void* d_ws, size_t ws_size,
                              hipStream_t stream) {
    const float* feat   = (const float*)d_in[0];
    const int*   target = (const int*)d_in[1];
    const float* negs   = (const float*)d_in[2];
    const int*   idxp   = (const int*)d_in[3];
    float* out = (float*)d_out;

    hipMemsetAsync(out, 0, sizeof(float), stream);
    neguni_main<<<dim3(N / ROWS), dim3(256), 0, stream>>>(feat, target, negs, idxp, out);
}

// Round 3
// 316.938 us; speedup vs baseline: 4.4938x; 4.4938x over previous
//
#include <hip/hip_runtime.h>
#include <hip/hip_bf16.h>
#include <math.h>

#define N 4096
#define D 128
#define NJ 4
#define KTOP 16

typedef __attribute__((ext_vector_type(8))) short bf16x8;
typedef __attribute__((ext_vector_type(4))) float f32x4;

// ws layout:
//   [0, 1MB)   fh   bf16 [N][D]        normalized feature rows
//   [1MB, 5MB) gh   bf16 [NJ][N][D]    normalized negative rows
//   [5MB, 6MB) top  f32  [NJ][N][KTOP] per-(j,row) sorted top-16 sims

// ---------------- prep: fp32 L2-normalize -> bf16 ----------------
__global__ __launch_bounds__(256) void neguni_prep(
    const float* __restrict__ feat, const float* __restrict__ negs,
    unsigned short* __restrict__ fh, unsigned short* __restrict__ gh)
{
    const int wave = threadIdx.x >> 6, lane = threadIdx.x & 63;
    const int row = blockIdx.x * 4 + wave;            // 0 .. 20479
    const float* src = (row < N) ? (feat + (size_t)row * D)
                                 : (negs + (size_t)(row - N) * D);
    unsigned short* dst = (row < N) ? (fh + (size_t)row * D)
                                    : (gh + (size_t)(row - N) * D);
    float a0 = src[2 * lane];
    float a1 = src[2 * lane + 1];
    float ss = a0 * a0 + a1 * a1;
    #pragma unroll
    for (int off = 32; off > 0; off >>= 1) ss += __shfl_xor(ss, off, 64);
    float inv = 1.0f / fmaxf(sqrtf(ss), 1e-12f);
    __hip_bfloat16 b0 = __float2bfloat16(a0 * inv);
    __hip_bfloat16 b1 = __float2bfloat16(a1 * inv);
    unsigned short u0 = *reinterpret_cast<unsigned short*>(&b0);
    unsigned short u1 = *reinterpret_cast<unsigned short*>(&b1);
    unsigned int packed = ((unsigned int)u1 << 16) | u0;
    ((unsigned int*)dst)[lane] = packed;
}

// ---------------- main: MFMA sims + fused streaming top-16 ----------------
// block: (j, 32-row tile). wave w: rows (w>>1)*16..+15, col-half w&1 (2048 cols).
// grid = NJ * (N/32) = 512 blocks.
__global__ __launch_bounds__(256) void neguni_main(
    const unsigned short* __restrict__ fh, const unsigned short* __restrict__ gh,
    const int* __restrict__ target, const int* __restrict__ idxp,
    float* __restrict__ topbuf)
{
    __shared__ float tops[32][2][KTOP];

    const int tid  = threadIdx.x;
    const int w    = tid >> 6;
    const int lane = tid & 63;
    const int j    = blockIdx.x & 3;
    const int rt   = blockIdx.x >> 2;                 // row tile 0..127
    const int r0   = rt * 32 + (w >> 1) * 16;         // wave's first row
    const int half = w & 1;
    const int idx  = idxp[0];
    const bool msk = (j == idx);

    // A fragments: 16 rows x K=128, persistent in registers.
    // A[m=lane&15][k=(lane>>4)*8 + i]; kstep s adds 32.
    bf16x8 afr[4];
    {
        const unsigned short* fr = fh + (size_t)(r0 + (lane & 15)) * D + (lane >> 4) * 8;
        afr[0] = *(const bf16x8*)(fr);
        afr[1] = *(const bf16x8*)(fr + 32);
        afr[2] = *(const bf16x8*)(fr + 64);
        afr[3] = *(const bf16x8*)(fr + 96);
    }
    // targets of the 4 C-rows this lane's accumulator regs cover
    int rtg[4];
    #pragma unroll
    for (int r = 0; r < 4; r++) rtg[r] = target[r0 + (lane >> 4) * 4 + r];

    float lst[4][KTOP];
    #pragma unroll
    for (int r = 0; r < 4; r++)
        #pragma unroll
        for (int k = 0; k < KTOP; k++) lst[r][k] = -3.0e38f;

    const unsigned short* gj = gh + (size_t)j * N * D;

    for (int ch = 0; ch < 32; ch++) {
        const int cbase = half * 2048 + ch * 64;

        f32x4 acc[4];
        #pragma unroll
        for (int t = 0; t < 4; t++) acc[t] = (f32x4){0.f, 0.f, 0.f, 0.f};

        #pragma unroll
        for (int s = 0; s < 4; s++) {
            #pragma unroll
            for (int t = 0; t < 4; t++) {
                const unsigned short* gp = gj
                    + (size_t)(cbase + t * 16 + (lane & 15)) * D
                    + s * 32 + (lane >> 4) * 8;
                bf16x8 b = *(const bf16x8*)gp;
                acc[t] = __builtin_amdgcn_mfma_f32_16x16x32_bf16(afr[s], b, acc[t], 0, 0, 0);
            }
        }

        #pragma unroll
        for (int t = 0; t < 4; t++) {
            const int c  = cbase + t * 16 + (lane & 15);
            const int tc = target[c];
            #pragma unroll
            for (int r = 0; r < 4; r++) {
                float v = acc[t][r];
                if (msk && tc == rtg[r]) v = -1e9f;
                if (v > lst[r][KTOP - 1]) {
                    #pragma unroll
                    for (int i = 0; i < KTOP; i++) {
                        float cur = lst[r][i];
                        bool  gt  = v > cur;
                        lst[r][i] = gt ? v : cur;
                        v         = gt ? cur : v;
                    }
                }
            }
        }
    }

    // merge 16 per-lane sorted lists within each 16-lane group (per reg row)
    const int g16 = (lane >> 4) * 16;   // group base lane
    #pragma unroll
    for (int r = 0; r < 4; r++) {
        const int lr = (w >> 1) * 16 + (lane >> 4) * 4 + r;   // local row 0..31
        #pragma unroll
        for (int it = 0; it < KTOP; it++) {
            float head = lst[r][0];
            float mx = head;
            mx = fmaxf(mx, __shfl_xor(mx, 8, 64));
            mx = fmaxf(mx, __shfl_xor(mx, 4, 64));
            mx = fmaxf(mx, __shfl_xor(mx, 2, 64));
            mx = fmaxf(mx, __shfl_xor(mx, 1, 64));
            unsigned long long b = __ballot(head == mx);
            unsigned grp = (unsigned)((b >> g16) & 0xFFFFull);
            int winner = g16 + (__ffs(grp) - 1);
            if (lane == winner) {
                #pragma unroll
                for (int i = 0; i < KTOP - 1; i++) lst[r][i] = lst[r][i + 1];
                lst[r][KTOP - 1] = -3.0e38f;
            }
            if ((lane & 15) == 0) tops[lr][half][it] = mx;
        }
    }
    __syncthreads();

    // merge the two sorted col-half lists -> global top-16, write out
    if (tid < 32) {
        const float* A = tops[tid][0];
        const float* B = tops[tid][1];
        float* outp = topbuf + ((size_t)j * N + rt * 32 + tid) * KTOP;
        int ia = 0, ib = 0;
        #pragma unroll
        for (int k = 0; k < KTOP; k++) {
            float va = A[ia], vb = B[ib];
            if (va >= vb) { outp[k] = va; ia++; }
            else          { outp[k] = vb; ib++; }
        }
    }
}

// ---------------- finalize: softmax-entropy across sets + decay reduce ----------------
__global__ __launch_bounds__(256) void neguni_fin(
    const float* __restrict__ topbuf, float* __restrict__ out)
{
    const int tid  = threadIdx.x;
    const int gid  = blockIdx.x * 256 + tid;   // 0..65535
    const int row  = gid >> 4;
    const int k    = gid & 15;

    float l0 = topbuf[((size_t)0 * N + row) * KTOP + k] * 100.0f;
    float l1 = topbuf[((size_t)1 * N + row) * KTOP + k] * 100.0f;
    float l2 = topbuf[((size_t)2 * N + row) * KTOP + k] * 100.0f;
    float l3 = topbuf[((size_t)3 * N + row) * KTOP + k] * 100.0f;
    float m  = fmaxf(fmaxf(l0, l1), fmaxf(l2, l3));
    float d0 = l0 - m, d1 = l1 - m, d2 = l2 - m, d3 = l3 - m;
    float e0 = expf(d0), e1 = expf(d1), e2 = expf(d2), e3 = expf(d3);
    float s  = e0 + e1 + e2 + e3;
    float ent = (e0 * d0 + e1 * d1 + e2 * d2 + e3 * d3) / s - logf(s);

    float wk   = powf(0.95f, (float)k);
    float Ssum = (1.0f - powf(0.95f, 16.0f)) / 0.05f;
    float val  = ent * wk / Ssum * (1.0f / (float)N);

    #pragma unroll
    for (int off = 32; off > 0; off >>= 1) val += __shfl_xor(val, off, 64);

    __shared__ float ws4[4];
    if ((tid & 63) == 0) ws4[tid >> 6] = val;
    __syncthreads();
    if (tid == 0) atomicAdd(out, ws4[0] + ws4[1] + ws4[2] + ws4[3]);
    if (blockIdx.x == 0 && tid == 0) atomicAdd(out, logf(4.0f));
}

extern "C" void kernel_launch(void* const* d_in, const int* in_sizes, int n_in,
                              void* d_out, int out_size, void* d_ws, size_t ws_size,
                              hipStream_t stream) {
    const float* feat   = (const float*)d_in[0];
    const int*   target = (const int*)d_in[1];
    const float* negs   = (const float*)d_in[2];
    const int*   idxp   = (const int*)d_in[3];
    float* out = (float*)d_out;

    unsigned short* fh = (unsigned short*)d_ws;
    unsigned short* gh = fh + (size_t)N * D;                  // +1 MB
    float* topbuf      = (float*)(gh + (size_t)NJ * N * D);   // +5 MB

    hipMemsetAsync(out, 0, sizeof(float), stream);
    // (N + NJ*N) rows = 20480, 4 rows/block -> 5120 blocks
    neguni_prep<<<dim3((N + NJ * N) / 4), dim3(256), 0, stream>>>(feat, negs, fh, gh);
    neguni_main<<<dim3(NJ * (N / 32)), dim3(256), 0, stream>>>(fh, gh, target, idxp, topbuf);
    neguni_fin<<<dim3((N * KTOP) / 256), dim3(256), 0, stream>>>(topbuf, out);
}

// Round 4
// 276.751 us; speedup vs baseline: 5.1463x; 1.1452x over previous
//
#include <hip/hip_runtime.h>
#include <hip/hip_bf16.h>
#include <math.h>

#define N 4096
#define D 128
#define NJ 4
#define KTOP 16
#define CSPLIT 4

typedef __attribute__((ext_vector_type(8))) short bf16x8;
typedef __attribute__((ext_vector_type(4))) float f32x4;

// ws layout:
//   [0, 1MB)   fh   bf16 [N][D]              normalized feature rows
//   [1MB, 5MB) gh   bf16 [NJ][N][D]          normalized negative rows
//   [5MB, 9MB) top  f32  [NJ][N][CSPLIT][16] partial sorted top-16 per col-split

// ---------------- prep: fp32 L2-normalize -> bf16 ----------------
__global__ __launch_bounds__(256) void neguni_prep(
    const float* __restrict__ feat, const float* __restrict__ negs,
    unsigned short* __restrict__ fh, unsigned short* __restrict__ gh)
{
    const int wave = threadIdx.x >> 6, lane = threadIdx.x & 63;
    const int row = blockIdx.x * 4 + wave;            // 0 .. 20479
    const float* src = (row < N) ? (feat + (size_t)row * D)
                                 : (negs + (size_t)(row - N) * D);
    unsigned short* dst = (row < N) ? (fh + (size_t)row * D)
                                    : (gh + (size_t)(row - N) * D);
    float a0 = src[2 * lane];
    float a1 = src[2 * lane + 1];
    float ss = a0 * a0 + a1 * a1;
    #pragma unroll
    for (int off = 32; off > 0; off >>= 1) ss += __shfl_xor(ss, off, 64);
    float inv = 1.0f / fmaxf(sqrtf(ss), 1e-12f);
    __hip_bfloat16 b0 = __float2bfloat16(a0 * inv);
    __hip_bfloat16 b1 = __float2bfloat16(a1 * inv);
    unsigned short u0 = *reinterpret_cast<unsigned short*>(&b0);
    unsigned short u1 = *reinterpret_cast<unsigned short*>(&b1);
    unsigned int packed = ((unsigned int)u1 << 16) | u0;
    ((unsigned int*)dst)[lane] = packed;
}

// ---------------- main: MFMA sims + filtered streaming top-16 ----------------
// block: (j, 32-row tile, col-split). wave w: rows (w>>1)*16..+15,
// col-half (w&1) of the block's 1024-col range (512 cols each).
// grid = NJ * (N/32) * CSPLIT = 2048 blocks.
__global__ __launch_bounds__(256) void neguni_main(
    const unsigned short* __restrict__ fh, const unsigned short* __restrict__ gh,
    const int* __restrict__ target, const int* __restrict__ idxp,
    float* __restrict__ topbuf)
{
    __shared__ float tops[32][2][KTOP];

    const int tid  = threadIdx.x;
    const int w    = tid >> 6;
    const int lane = tid & 63;
    const int j    = blockIdx.x & 3;
    const int rt   = (blockIdx.x >> 2) & 127;         // row tile 0..127
    const int cs   = blockIdx.x >> 9;                 // col split 0..3
    const int r0   = rt * 32 + (w >> 1) * 16;
    const int half = w & 1;
    const int cb0  = cs * 1024 + half * 512;
    const int idx  = idxp[0];
    const bool msk = (j == idx);

    // A fragments: 16 rows x K=128, persistent. A[m=lane&15][k=(lane>>4)*8+i]
    bf16x8 afr[4];
    {
        const unsigned short* fr = fh + (size_t)(r0 + (lane & 15)) * D + (lane >> 4) * 8;
        afr[0] = *(const bf16x8*)(fr);
        afr[1] = *(const bf16x8*)(fr + 32);
        afr[2] = *(const bf16x8*)(fr + 64);
        afr[3] = *(const bf16x8*)(fr + 96);
    }
    int rtg[4];
    #pragma unroll
    for (int r = 0; r < 4; r++) rtg[r] = target[r0 + (lane >> 4) * 4 + r];

    float lst[4][KTOP];
    float Tr[4];
    #pragma unroll
    for (int r = 0; r < 4; r++) {
        Tr[r] = -3.0e38f;
        #pragma unroll
        for (int k = 0; k < KTOP; k++) lst[r][k] = -3.0e38f;
    }

    const unsigned short* gj = gh + (size_t)j * N * D;

    for (int ch = 0; ch < 8; ch++) {
        const int cbase = cb0 + ch * 64;

        f32x4 acc[4];
        #pragma unroll
        for (int t = 0; t < 4; t++) acc[t] = (f32x4){0.f, 0.f, 0.f, 0.f};

        #pragma unroll
        for (int s = 0; s < 4; s++) {
            #pragma unroll
            for (int t = 0; t < 4; t++) {
                const unsigned short* gp = gj
                    + (size_t)(cbase + t * 16 + (lane & 15)) * D
                    + s * 32 + (lane >> 4) * 8;
                bf16x8 b = *(const bf16x8*)gp;
                acc[t] = __builtin_amdgcn_mfma_f32_16x16x32_bf16(afr[s], b, acc[t], 0, 0, 0);
            }
        }

        #pragma unroll
        for (int t = 0; t < 4; t++) {
            const int c  = cbase + t * 16 + (lane & 15);
            const int tc = target[c];
            #pragma unroll
            for (int r = 0; r < 4; r++) {
                float v = acc[t][r];
                if (msk && tc == rtg[r]) v = -1e9f;
                // Group-threshold filter: Tr[r] >= some lane's 16th-best, and
                // that lane's sorted list only improves -> v <= Tr can never
                // be in the union top-16. Exact.
                if (v > fmaxf(Tr[r], lst[r][KTOP - 1])) {
                    #pragma unroll
                    for (int i = 0; i < KTOP; i++) {
                        float cur = lst[r][i];
                        bool  gt  = v > cur;
                        lst[r][i] = gt ? v : cur;
                        v         = gt ? cur : v;
                    }
                }
            }
        }

        // refresh group threshold (max over 16-lane group of each lane's 16th)
        #pragma unroll
        for (int r = 0; r < 4; r++) {
            float g = lst[r][KTOP - 1];
            g = fmaxf(g, __shfl_xor(g, 8, 64));
            g = fmaxf(g, __shfl_xor(g, 4, 64));
            g = fmaxf(g, __shfl_xor(g, 2, 64));
            g = fmaxf(g, __shfl_xor(g, 1, 64));
            Tr[r] = g;
        }
    }

    // merge 16 per-lane sorted lists within each 16-lane group (per reg row)
    const int g16 = (lane >> 4) * 16;
    #pragma unroll
    for (int r = 0; r < 4; r++) {
        const int lr = (w >> 1) * 16 + (lane >> 4) * 4 + r;   // local row 0..31
        #pragma unroll
        for (int it = 0; it < KTOP; it++) {
            float head = lst[r][0];
            float mx = head;
            mx = fmaxf(mx, __shfl_xor(mx, 8, 64));
            mx = fmaxf(mx, __shfl_xor(mx, 4, 64));
            mx = fmaxf(mx, __shfl_xor(mx, 2, 64));
            mx = fmaxf(mx, __shfl_xor(mx, 1, 64));
            unsigned long long b = __ballot(head == mx);
            unsigned grp = (unsigned)((b >> g16) & 0xFFFFull);
            int winner = g16 + (__ffs(grp) - 1);
            if (lane == winner) {
                #pragma unroll
                for (int i = 0; i < KTOP - 1; i++) lst[r][i] = lst[r][i + 1];
                lst[r][KTOP - 1] = -3.0e38f;
            }
            if ((lane & 15) == 0) tops[lr][half][it] = mx;
        }
    }
    __syncthreads();

    // merge the two sorted col-half lists -> sorted partial top-16, write out
    if (tid < 32) {
        const float* A = tops[tid][0];
        const float* B = tops[tid][1];
        float* outp = topbuf + (((size_t)j * N + rt * 32 + tid) * CSPLIT + cs) * KTOP;
        int ia = 0, ib = 0;
        #pragma unroll
        for (int k = 0; k < KTOP; k++) {
            float va = A[ia], vb = B[ib];
            if (va >= vb) { outp[k] = va; ia++; }
            else          { outp[k] = vb; ib++; }
        }
    }
}

// ---------------- finalize: 4-way merge of partials + entropy reduce ----------------
// grid = 64 blocks x 256 threads. Thread t: j = t>>6, row_l = t&63.
__global__ __launch_bounds__(256) void neguni_fin(
    const float* __restrict__ topbuf, float* __restrict__ out)
{
    __shared__ float buf[256][69];    // 4 lists of 17 (16 + sentinel) per thread
    __shared__ float mm[64][65];      // merged [row_l][k*4+j], padded
    __shared__ float red[4];

    const int t     = threadIdx.x;
    const int j     = t >> 6;
    const int row_l = t & 63;
    const int row   = blockIdx.x * 64 + row_l;

    // the 4 cs-partials of (j,row) are 64 contiguous floats
    const float4* src = (const float4*)(topbuf + ((size_t)j * N + row) * (CSPLIT * KTOP));
    #pragma unroll
    for (int q = 0; q < 16; q++) {
        float4 v = src[q];
        const int base = (q >> 2) * 17 + (q & 3) * 4;
        buf[t][base + 0] = v.x;
        buf[t][base + 1] = v.y;
        buf[t][base + 2] = v.z;
        buf[t][base + 3] = v.w;
    }
    buf[t][16] = -3.0e38f;
    buf[t][33] = -3.0e38f;
    buf[t][50] = -3.0e38f;
    buf[t][67] = -3.0e38f;

    // serial 4-way merge of the sorted (desc) lists -> global top-16
    {
        float* bp = &buf[t][0];
        int i0 = 0, i1 = 17, i2 = 34, i3 = 51;
        for (int k = 0; k < KTOP; k++) {
            float v0 = bp[i0], v1 = bp[i1], v2 = bp[i2], v3 = bp[i3];
            float m01 = fmaxf(v0, v1);
            float m23 = fmaxf(v2, v3);
            float mx  = fmaxf(m01, m23);
            if      (mx == v0) i0++;
            else if (mx == v1) i1++;
            else if (mx == v2) i2++;
            else               i3++;
            mm[row_l][k * 4 + j] = mx;
        }
    }
    __syncthreads();

    // entropy across sets, decay-weighted; 1024 (row,k) items, 4 per thread
    float val = 0.f;
    const float Ssum = (1.0f - powf(0.95f, 16.0f)) / 0.05f;
    #pragma unroll
    for (int i = 0; i < 4; i++) {
        const int idx = t + i * 256;
        const int rl  = idx & 63;
        const int k   = idx >> 6;
        float l0 = mm[rl][k * 4 + 0] * 100.0f;
        float l1 = mm[rl][k * 4 + 1] * 100.0f;
        float l2 = mm[rl][k * 4 + 2] * 100.0f;
        float l3 = mm[rl][k * 4 + 3] * 100.0f;
        float m  = fmaxf(fmaxf(l0, l1), fmaxf(l2, l3));
        float d0 = l0 - m, d1 = l1 - m, d2 = l2 - m, d3 = l3 - m;
        float e0 = expf(d0), e1 = expf(d1), e2 = expf(d2), e3 = expf(d3);
        float s  = e0 + e1 + e2 + e3;
        float ent = (e0 * d0 + e1 * d1 + e2 * d2 + e3 * d3) / s - logf(s);
        val += ent * powf(0.95f, (float)k);
    }
    val *= 1.0f / (Ssum * (float)N);

    #pragma unroll
    for (int off = 32; off > 0; off >>= 1) val += __shfl_xor(val, off, 64);
    if ((t & 63) == 0) red[t >> 6] = val;
    __syncthreads();
    if (t == 0) atomicAdd(out, red[0] + red[1] + red[2] + red[3]);
    if (blockIdx.x == 0 && t == 0) atomicAdd(out, logf(4.0f));
}

extern "C" void kernel_launch(void* const* d_in, const int* in_sizes, int n_in,
                              void* d_out, int out_size, void* d_ws, size_t ws_size,
                              hipStream_t stream) {
    const float* feat   = (const float*)d_in[0];
    const int*   target = (const int*)d_in[1];
    const float* negs   = (const float*)d_in[2];
    const int*   idxp   = (const int*)d_in[3];
    float* out = (float*)d_out;

    unsigned short* fh = (unsigned short*)d_ws;
    unsigned short* gh = fh + (size_t)N * D;                  // +1 MB
    float* topbuf      = (float*)(gh + (size_t)NJ * N * D);   // +5 MB, 4 MB long

    hipMemsetAsync(out, 0, sizeof(float), stream);
    neguni_prep<<<dim3((N + NJ * N) / 4), dim3(256), 0, stream>>>(feat, negs, fh, gh);
    neguni_main<<<dim3(NJ * (N / 32) * CSPLIT), dim3(256), 0, stream>>>(fh, gh, target, idxp, topbuf);
    neguni_fin<<<dim3(N / 64), dim3(256), 0, stream>>>(topbuf, out);
}

// Round 5
// 204.194 us; speedup vs baseline: 6.9750x; 1.3553x over previous
//
#include <hip/hip_runtime.h>
#include <hip/hip_bf16.h>
#include <math.h>

#define N 4096
#define D 128
#define NJ 4
#define KTOP 16
#define CSPLIT 2

typedef __attribute__((ext_vector_type(8))) short bf16x8;
typedef __attribute__((ext_vector_type(4))) float f32x4;

// ws layout:
//   [0, 1MB)   fh   bf16 [N][D]              normalized feature rows
//   [1MB, 5MB) gh   bf16 [NJ][N][D]          normalized negative rows
//   [5MB, 7MB) top  f32  [NJ][N][CSPLIT][16] partial sorted top-16 per col-split

// descending bitonic sort of 16 register floats (fully unrolled, branchless)
__device__ __forceinline__ void bitonic_sort16_desc(float* a) {
    #pragma unroll
    for (int k = 2; k <= 16; k <<= 1) {
        #pragma unroll
        for (int jj = k >> 1; jj > 0; jj >>= 1) {
            #pragma unroll
            for (int i = 0; i < 16; i++) {
                int l = i ^ jj;
                if (l > i) {
                    bool up = ((i & k) == 0);
                    float x = a[i], y = a[l];
                    float mx = fmaxf(x, y), mn = fminf(x, y);
                    a[i] = up ? mx : mn;
                    a[l] = up ? mn : mx;
                }
            }
        }
    }
}

// clean a bitonic 16-sequence into descending order
__device__ __forceinline__ void bitonic_clean16_desc(float* a) {
    #pragma unroll
    for (int jj = 8; jj > 0; jj >>= 1) {
        #pragma unroll
        for (int i = 0; i < 16; i++) {
            int l = i ^ jj;
            if (l > i) {
                float x = a[i], y = a[l];
                a[i] = fmaxf(x, y);
                a[l] = fminf(x, y);
            }
        }
    }
}

// ---------------- prep: fp32 L2-normalize -> bf16 (2 rows per 32-lane group) ----------------
__global__ __launch_bounds__(256) void neguni_prep(
    const float* __restrict__ feat, const float* __restrict__ negs,
    unsigned short* __restrict__ fh, unsigned short* __restrict__ gh)
{
    const int g   = threadIdx.x >> 5;
    const int l32 = threadIdx.x & 31;
    const int row = blockIdx.x * 8 + g;          // 0 .. 20479
    const float* src = (row < N) ? (feat + (size_t)row * D)
                                 : (negs + (size_t)(row - N) * D);
    unsigned short* dst = (row < N) ? (fh + (size_t)row * D)
                                    : (gh + (size_t)(row - N) * D);
    float4 v = ((const float4*)src)[l32];
    float ss = v.x * v.x + v.y * v.y + v.z * v.z + v.w * v.w;
    #pragma unroll
    for (int off = 16; off > 0; off >>= 1) ss += __shfl_xor(ss, off, 64);
    float inv = 1.0f / fmaxf(sqrtf(ss), 1e-12f);
    __hip_bfloat16 b0 = __float2bfloat16(v.x * inv);
    __hip_bfloat16 b1 = __float2bfloat16(v.y * inv);
    __hip_bfloat16 b2 = __float2bfloat16(v.z * inv);
    __hip_bfloat16 b3 = __float2bfloat16(v.w * inv);
    unsigned int lo = ((unsigned int)*(unsigned short*)&b1 << 16) | *(unsigned short*)&b0;
    unsigned int hi = ((unsigned int)*(unsigned short*)&b3 << 16) | *(unsigned short*)&b2;
    uint2 p; p.x = lo; p.y = hi;
    ((uint2*)dst)[l32] = p;
}

// ---------------- main: transposed MFMA + lane-local batched top-16 ----------------
// block: (j, 16-feature-row tile, col-split). wave w: 512-candidate range.
// C layout: row = candidate (quad*4+reg), col = feature (lane&15)
// -> each lane owns ONE feature row's values. grid = NJ*(N/16)*CSPLIT = 2048.
__global__ __launch_bounds__(256) void neguni_main(
    const unsigned short* __restrict__ fh, const unsigned short* __restrict__ gh,
    const int* __restrict__ target, const int* __restrict__ idxp,
    float* __restrict__ topbuf)
{
    __shared__ float tops[4][16][17];

    const int tid   = threadIdx.x;
    const int w     = tid >> 6;
    const int lane  = tid & 63;
    const int col16 = lane & 15;     // feature row within tile
    const int quad  = lane >> 4;

    const int j   = blockIdx.x & 3;
    const int ft  = (blockIdx.x >> 2) & 255;
    const int cs  = blockIdx.x >> 10;
    const int r0  = ft * 16;
    const int c0  = cs * 2048 + w * 512;
    const int idx = idxp[0];
    const bool msk = (j == idx);

    // B fragments: 16 feature rows, persistent (same addressing validated R2-4)
    bf16x8 bfr[4];
    {
        const unsigned short* fr = fh + (size_t)(r0 + col16) * D + quad * 8;
        bfr[0] = *(const bf16x8*)(fr);
        bfr[1] = *(const bf16x8*)(fr + 32);
        bfr[2] = *(const bf16x8*)(fr + 64);
        bfr[3] = *(const bf16x8*)(fr + 96);
    }
    const int rtg = target[r0 + col16];

    float lst[KTOP];
    #pragma unroll
    for (int i = 0; i < KTOP; i++) lst[i] = -3.0e38f;

    const unsigned short* gj = gh + (size_t)j * N * D;

    for (int ch = 0; ch < 8; ch++) {
        const int cbase = c0 + ch * 64;

        f32x4 acc[4];
        #pragma unroll
        for (int t = 0; t < 4; t++) acc[t] = (f32x4){0.f, 0.f, 0.f, 0.f};

        #pragma unroll
        for (int s = 0; s < 4; s++) {
            #pragma unroll
            for (int t = 0; t < 4; t++) {
                // A operand: candidate rows (same fragment shape as validated loads)
                const unsigned short* ap = gj
                    + (size_t)(cbase + t * 16 + col16) * D
                    + s * 32 + quad * 8;
                bf16x8 a = *(const bf16x8*)ap;
                acc[t] = __builtin_amdgcn_mfma_f32_16x16x32_bf16(a, bfr[s], acc[t], 0, 0, 0);
            }
        }

        // gather this lane's 16 values (all for feature row r0+col16)
        float s16[16];
        #pragma unroll
        for (int t = 0; t < 4; t++) {
            s16[t * 4 + 0] = acc[t][0];
            s16[t * 4 + 1] = acc[t][1];
            s16[t * 4 + 2] = acc[t][2];
            s16[t * 4 + 3] = acc[t][3];
        }
        if (msk) {
            #pragma unroll
            for (int t = 0; t < 4; t++) {
                int4 tc = *(const int4*)(target + cbase + t * 16 + quad * 4);
                if (tc.x == rtg) s16[t * 4 + 0] = -1e9f;
                if (tc.y == rtg) s16[t * 4 + 1] = -1e9f;
                if (tc.z == rtg) s16[t * 4 + 2] = -1e9f;
                if (tc.w == rtg) s16[t * 4 + 3] = -1e9f;
            }
        }

        // exact top-16(lst U s16): sort incoming, elementwise-max against
        // reversed list (bitonic valley), clean.
        bitonic_sort16_desc(s16);
        float mg[16];
        #pragma unroll
        for (int i = 0; i < 16; i++) mg[i] = fmaxf(lst[i], s16[15 - i]);
        bitonic_clean16_desc(mg);
        #pragma unroll
        for (int i = 0; i < 16; i++) lst[i] = mg[i];
    }

    // intra-wave merge across quads (lanes with same col16): 2 shfl levels
    #pragma unroll
    for (int off = 16; off <= 32; off <<= 1) {
        float mg[16];
        #pragma unroll
        for (int i = 0; i < 16; i++)
            mg[i] = fmaxf(lst[i], __shfl_xor(lst[15 - i], off, 64));
        bitonic_clean16_desc(mg);
        #pragma unroll
        for (int i = 0; i < 16; i++) lst[i] = mg[i];
    }

    if (lane < 16) {
        #pragma unroll
        for (int i = 0; i < 16; i++) tops[w][lane][i] = lst[i];
        tops[w][lane][16] = -3.0e38f;   // sentinel
    }
    __syncthreads();

    // cross-wave 4-way serial merge (waves cover disjoint candidate ranges)
    if (tid < 16) {
        int i0 = 0, i1 = 0, i2 = 0, i3 = 0;
        float* outp = topbuf + (((size_t)j * N + r0 + tid) * CSPLIT + cs) * KTOP;
        #pragma unroll
        for (int k = 0; k < KTOP; k++) {
            float v0 = tops[0][tid][i0], v1 = tops[1][tid][i1];
            float v2 = tops[2][tid][i2], v3 = tops[3][tid][i3];
            float m01 = fmaxf(v0, v1), m23 = fmaxf(v2, v3);
            float mx  = fmaxf(m01, m23);
            if      (mx == v0) i0++;
            else if (mx == v1) i1++;
            else if (mx == v2) i2++;
            else               i3++;
            outp[k] = mx;
        }
    }
}

// ---------------- finalize: 2-way merge of partials + entropy reduce ----------------
__global__ __launch_bounds__(256) void neguni_fin(
    const float* __restrict__ topbuf, float* __restrict__ out)
{
    __shared__ float buf[256][35];    // 2 lists of 17 (16 + sentinel) per thread
    __shared__ float mm[64][65];      // merged [row_l][k*4+j], padded
    __shared__ float red[4];

    const int t     = threadIdx.x;
    const int j     = t >> 6;
    const int row_l = t & 63;
    const int row   = blockIdx.x * 64 + row_l;

    const float4* src = (const float4*)(topbuf + ((size_t)j * N + row) * (CSPLIT * KTOP));
    #pragma unroll
    for (int q = 0; q < 8; q++) {
        float4 v = src[q];
        const int base = (q >> 2) * 17 + (q & 3) * 4;
        buf[t][base + 0] = v.x;
        buf[t][base + 1] = v.y;
        buf[t][base + 2] = v.z;
        buf[t][base + 3] = v.w;
    }
    buf[t][16] = -3.0e38f;
    buf[t][33] = -3.0e38f;

    {
        int ia = 0, ib = 17;
        #pragma unroll
        for (int k = 0; k < KTOP; k++) {
            float va = buf[t][ia], vb = buf[t][ib];
            bool ta = va >= vb;
            mm[row_l][k * 4 + j] = ta ? va : vb;
            if (ta) ia++; else ib++;
        }
    }
    __syncthreads();

    float val = 0.f;
    const float Ssum = (1.0f - powf(0.95f, 16.0f)) / 0.05f;
    #pragma unroll
    for (int i = 0; i < 4; i++) {
        const int idx = t + i * 256;
        const int rl  = idx & 63;
        const int k   = idx >> 6;
        float l0 = mm[rl][k * 4 + 0] * 100.0f;
        float l1 = mm[rl][k * 4 + 1] * 100.0f;
        float l2 = mm[rl][k * 4 + 2] * 100.0f;
        float l3 = mm[rl][k * 4 + 3] * 100.0f;
        float m  = fmaxf(fmaxf(l0, l1), fmaxf(l2, l3));
        float d0 = l0 - m, d1 = l1 - m, d2 = l2 - m, d3 = l3 - m;
        float e0 = expf(d0), e1 = expf(d1), e2 = expf(d2), e3 = expf(d3);
        float s  = e0 + e1 + e2 + e3;
        float ent = (e0 * d0 + e1 * d1 + e2 * d2 + e3 * d3) / s - logf(s);
        val += ent * powf(0.95f, (float)k);
    }
    val *= 1.0f / (Ssum * (float)N);

    #pragma unroll
    for (int off = 32; off > 0; off >>= 1) val += __shfl_xor(val, off, 64);
    if ((t & 63) == 0) red[t >> 6] = val;
    __syncthreads();
    if (t == 0) atomicAdd(out, red[0] + red[1] + red[2] + red[3]);
    if (blockIdx.x == 0 && t == 0) atomicAdd(out, logf(4.0f));
}

extern "C" void kernel_launch(void* const* d_in, const int* in_sizes, int n_in,
                              void* d_out, int out_size, void* d_ws, size_t ws_size,
                              hipStream_t stream) {
    const float* feat   = (const float*)d_in[0];
    const int*   target = (const int*)d_in[1];
    const float* negs   = (const float*)d_in[2];
    const int*   idxp   = (const int*)d_in[3];
    float* out = (float*)d_out;

    unsigned short* fh = (unsigned short*)d_ws;
    unsigned short* gh = fh + (size_t)N * D;                  // +1 MB
    float* topbuf      = (float*)(gh + (size_t)NJ * N * D);   // +5 MB, 2 MB long

    hipMemsetAsync(out, 0, sizeof(float), stream);
    neguni_prep<<<dim3((N + NJ * N) / 8), dim3(256), 0, stream>>>(feat, negs, fh, gh);
    neguni_main<<<dim3(NJ * (N / 16) * CSPLIT), dim3(256), 0, stream>>>(fh, gh, target, idxp, topbuf);
    neguni_fin<<<dim3(N / 64), dim3(256), 0, stream>>>(topbuf, out);
}